// Round 5
// baseline (884.170 us; speedup 1.0000x reference)
//
#include <hip/hip_runtime.h>
#include <hip/hip_bf16.h>

typedef unsigned short u16;
typedef u16 u16x8 __attribute__((ext_vector_type(8)));
typedef u16 u16x4 __attribute__((ext_vector_type(4)));
typedef float f32x4 __attribute__((ext_vector_type(4)));
typedef __bf16 bf16x8 __attribute__((ext_vector_type(8)));

// ---------- helpers ----------
static __device__ __forceinline__ u16 f2bf(float f) {
  __hip_bfloat16 h = __float2bfloat16(f);
  return __builtin_bit_cast(u16, h);
}

static __device__ __forceinline__ f32x4 mfma16x16(u16x8 a, u16x8 b, f32x4 c) {
  return __builtin_amdgcn_mfma_f32_16x16x32_bf16(
      __builtin_bit_cast(bf16x8, a), __builtin_bit_cast(bf16x8, b), c, 0, 0, 0);
}

// ---------- group-norm statistics ----------
// blocks 0..31: video groups (16 ch x 16 frames x 1024 hw = 262144 elems)
// blocks 32..63: audio groups (16 ch x 4096 = 65536 elems)
__global__ void __launch_bounds__(256) stats_kernel(
    const float* __restrict__ video, const float* __restrict__ audio,
    float* __restrict__ stats) {
  int g = blockIdx.x;
  int tid = threadIdx.x;
  float s1 = 0.f, s2 = 0.f;
  if (g < 32) {
    int gc = g * 16;
    for (int i = tid; i < 262144; i += 256) {
      int f = i >> 14;
      int r = i & 16383;
      int c = gc + (r >> 10);
      int hw = r & 1023;
      float x = video[(size_t)f * 524288 + (size_t)c * 1024 + hw];
      s1 += x; s2 += x * x;
    }
  } else {
    int gc = (g - 32) * 16;
    for (int i = tid; i < 65536; i += 256) {
      int c = gc + (i >> 12);
      int la = i & 4095;
      float x = audio[(size_t)c * 4096 + la];
      s1 += x; s2 += x * x;
    }
  }
  __shared__ float r1[256], r2[256];
  r1[tid] = s1; r2[tid] = s2;
  __syncthreads();
  for (int s = 128; s > 0; s >>= 1) {
    if (tid < s) { r1[tid] += r1[tid + s]; r2[tid] += r2[tid + s]; }
    __syncthreads();
  }
  if (tid == 0) {
    float n = (g < 32) ? 262144.f : 65536.f;
    float mu = r1[0] / n;
    float var = r2[0] / n - mu * mu;
    stats[2 * g] = mu;
    stats[2 * g + 1] = rsqrtf(var + 1e-5f);
  }
}

// ---------- normalize + transpose to XT[t][c] (bf16) ----------
__global__ void __launch_bounds__(256) norm_video(
    const float* __restrict__ video, const float* __restrict__ gamma,
    const float* __restrict__ beta, const float* __restrict__ stats,
    u16* __restrict__ XT) {
  __shared__ float tile[64][65];
  int bid = blockIdx.x;
  int t0 = (bid % 256) * 64;  // token tile (within video, 16384 tokens)
  int c0 = (bid / 256) * 64;  // channel tile
  int f = t0 >> 10;
  int hw0 = t0 & 1023;
  int tx = threadIdx.x & 63, ty = threadIdx.x >> 6;
#pragma unroll
  for (int p = 0; p < 16; ++p) {
    int cl = p * 4 + ty;
    int c = c0 + cl;
    float x = video[(size_t)f * 524288 + (size_t)c * 1024 + hw0 + tx];
    int g = c >> 4;
    float xn = (x - stats[2 * g]) * stats[2 * g + 1] * gamma[c] + beta[c];
    tile[tx][cl] = xn;
  }
  __syncthreads();
#pragma unroll
  for (int p = 0; p < 16; ++p) {
    int tl = p * 4 + ty;
    XT[(size_t)(t0 + tl) * 512 + c0 + tx] = f2bf(tile[tl][tx]);
  }
}

__global__ void __launch_bounds__(256) norm_audio(
    const float* __restrict__ audio, const float* __restrict__ gamma,
    const float* __restrict__ beta, const float* __restrict__ stats,
    u16* __restrict__ XT) {
  __shared__ float tile[64][65];
  int bid = blockIdx.x;
  int t0 = (bid % 64) * 64;
  int c0 = (bid / 64) * 64;
  int tx = threadIdx.x & 63, ty = threadIdx.x >> 6;
#pragma unroll
  for (int p = 0; p < 16; ++p) {
    int cl = p * 4 + ty;
    int c = c0 + cl;
    float x = audio[(size_t)c * 4096 + t0 + tx];
    int g = 32 + (c >> 4);
    float xn = (x - stats[2 * g]) * stats[2 * g + 1] * gamma[c] + beta[c];
    tile[tx][cl] = xn;
  }
  __syncthreads();
#pragma unroll
  for (int p = 0; p < 16; ++p) {
    int tl = p * 4 + ty;
    XT[(size_t)(16384 + t0 + tl) * 512 + c0 + tx] = f2bf(tile[tl][tx]);
  }
}

// ---------- fused fp32 -> bf16 weight convert (Wv|Wa|Pv|Pa contiguous dst) ----------
__global__ void __launch_bounds__(256) cvt_all(
    const float* __restrict__ s0, const float* __restrict__ s1,
    const float* __restrict__ s2, const float* __restrict__ s3,
    u16* __restrict__ dst) {
  int i = (blockIdx.x * 256 + threadIdx.x) * 4;  // [0, 2097152)
  const float* src;
  int off;
  if (i < 786432)       { src = s0; off = 0; }
  else if (i < 1572864) { src = s1; off = 786432; }
  else if (i < 1835008) { src = s2; off = 1572864; }
  else                  { src = s3; off = 1835008; }
  float4 v = *(const float4*)&src[i - off];
  u16x4 pk;
  pk[0] = f2bf(v.x); pk[1] = f2bf(v.y); pk[2] = f2bf(v.z); pk[3] = f2bf(v.w);
  *(u16x4*)&dst[i] = pk;
}

// ---------- GEMM  C[m][n] = sum_k A[m][k] * B[n][k]   (K = 512) ----------
// MODE 0: qkv epilogue  -> Q[t][c] (x0.125), K[t][c], Vt[c][t], +bias
// MODE 2: video proj    -> d_out video += residual, +bias
// MODE 3: audio proj    -> d_out audio += residual, +bias
template <int MODE>
__global__ void __launch_bounds__(256, 2) gemm_bt(
    const u16* __restrict__ A, const u16* __restrict__ B,
    const float* __restrict__ bias, u16* __restrict__ Qo,
    u16* __restrict__ Ko, u16* __restrict__ Vt, float* __restrict__ FO,
    const float* __restrict__ RES, int t_off) {
  __shared__ u16 As[128][72];
  __shared__ u16 Bs[128][72];
  const int tid = threadIdx.x;
  const int lane = tid & 63;
  const int w = tid >> 6;
  const int wr = w >> 1, wc = w & 1;
  const int col = lane & 15, qg = lane >> 4;
  const int m0 = blockIdx.y * 128;
  const int n0 = blockIdx.x * 128;
  f32x4 acc[4][4] = {};
  for (int k0 = 0; k0 < 512; k0 += 64) {
#pragma unroll
    for (int p = 0; p < 4; ++p) {
      int chunk = p * 256 + tid;
      int row = chunk >> 3;
      int kk = (chunk & 7) * 8;
      *(u16x8*)&As[row][kk] = *(const u16x8*)&A[(size_t)(m0 + row) * 512 + k0 + kk];
      *(u16x8*)&Bs[row][kk] = *(const u16x8*)&B[(size_t)(n0 + row) * 512 + k0 + kk];
    }
    __syncthreads();
#pragma unroll
    for (int ks = 0; ks < 2; ++ks) {
      u16x8 af[4], bf[4];
#pragma unroll
      for (int mt = 0; mt < 4; ++mt)
        af[mt] = *(const u16x8*)&As[wr * 64 + mt * 16 + col][ks * 32 + qg * 8];
#pragma unroll
      for (int nt = 0; nt < 4; ++nt)
        bf[nt] = *(const u16x8*)&Bs[wc * 64 + nt * 16 + col][ks * 32 + qg * 8];
#pragma unroll
      for (int mt = 0; mt < 4; ++mt)
#pragma unroll
        for (int nt = 0; nt < 4; ++nt)
          acc[mt][nt] = mfma16x16(af[mt], bf[nt], acc[mt][nt]);
    }
    __syncthreads();
  }
  // epilogue
#pragma unroll
  for (int mt = 0; mt < 4; ++mt) {
    int o = m0 + wr * 64 + mt * 16 + qg * 4;
#pragma unroll
    for (int nt = 0; nt < 4; ++nt) {
      int t = n0 + wc * 64 + nt * 16 + col;
      float v0 = acc[mt][nt][0] + bias[o + 0];
      float v1 = acc[mt][nt][1] + bias[o + 1];
      float v2 = acc[mt][nt][2] + bias[o + 2];
      float v3 = acc[mt][nt][3] + bias[o + 3];
      if constexpr (MODE == 0) {
        int tg = t_off + t;
        if (o < 512) {
          // fold logit scale (1/8, exact in bf16) into Q
          u16x4 pk;
          pk[0] = f2bf(v0 * 0.125f); pk[1] = f2bf(v1 * 0.125f);
          pk[2] = f2bf(v2 * 0.125f); pk[3] = f2bf(v3 * 0.125f);
          *(u16x4*)&Qo[(size_t)tg * 512 + o] = pk;
        } else if (o < 1024) {
          u16x4 pk;
          pk[0] = f2bf(v0); pk[1] = f2bf(v1); pk[2] = f2bf(v2); pk[3] = f2bf(v3);
          *(u16x4*)&Ko[(size_t)tg * 512 + (o - 512)] = pk;
        } else {
          int vo = o - 1024;
          Vt[(size_t)(vo + 0) * 20480 + tg] = f2bf(v0);
          Vt[(size_t)(vo + 1) * 20480 + tg] = f2bf(v1);
          Vt[(size_t)(vo + 2) * 20480 + tg] = f2bf(v2);
          Vt[(size_t)(vo + 3) * 20480 + tg] = f2bf(v3);
        }
      } else if constexpr (MODE == 2) {
        int f = t >> 10, hw = t & 1023;
        size_t i0 = ((size_t)(f * 512 + o)) * 1024 + hw;
        FO[i0]        = RES[i0]        + v0;
        FO[i0 + 1024] = RES[i0 + 1024] + v1;
        FO[i0 + 2048] = RES[i0 + 2048] + v2;
        FO[i0 + 3072] = RES[i0 + 3072] + v3;
      } else {
        size_t i0 = (size_t)o * 4096 + t;
        FO[i0]         = RES[i0]         + v0;
        FO[i0 + 4096]  = RES[i0 + 4096]  + v1;
        FO[i0 + 8192]  = RES[i0 + 8192]  + v2;
        FO[i0 + 12288] = RES[i0 + 12288] + v3;
      }
    }
  }
}

// ---------- flash attention (windowed, wrap-around gather, no mask) ----------
// Q pre-scaled by 0.125. Block = 4 waves, wave owns 16 q-rows.
// key token index: kt = kbase + (f*kstep + s) % kmod
__global__ void __launch_bounds__(256, 2) flash_attn(
    const u16* __restrict__ Q, const u16* __restrict__ K,
    const u16* __restrict__ Vt, u16* __restrict__ AO, int Tq, int W,
    int qt_base, int kbase, int kstep, int kmod, int nttiles) {
  __shared__ u16 P[4][16][72];
  int bid = blockIdx.x;
  int tt = bid % nttiles;
  int f = (bid / nttiles) & 15;
  int h = bid / (nttiles * 16);
  int tid = threadIdx.x;
  int lane = tid & 63;
  int w = tid >> 6;
  int col = lane & 15, qg = lane >> 4;
  int ch0 = h * 64;
  int qt0 = qt_base + f * Tq + tt * 64 + w * 16;
  u16x8 qf[2];
#pragma unroll
  for (int kk = 0; kk < 2; ++kk)
    qf[kk] = *(const u16x8*)&Q[(size_t)(qt0 + col) * 512 + ch0 + kk * 32 + qg * 8];
  f32x4 oacc[4] = {};
  float m_[4], l_[4];
#pragma unroll
  for (int j = 0; j < 4; ++j) { m_[j] = -1e30f; l_[j] = 0.f; }
  int fk = f * kstep;
  for (int s0 = 0; s0 < W; s0 += 64) {
    f32x4 sacc[4] = {};
#pragma unroll
    for (int st = 0; st < 4; ++st) {
      int s = s0 + st * 16 + col;
      int kt = kbase + (fk + s) % kmod;
      const u16* kr = &K[(size_t)kt * 512 + ch0];
#pragma unroll
      for (int kk = 0; kk < 2; ++kk) {
        u16x8 bfr = *(const u16x8*)&kr[kk * 32 + qg * 8];
        sacc[st] = mfma16x16(qf[kk], bfr, sacc[st]);
      }
    }
    float corr[4];
#pragma unroll
    for (int j = 0; j < 4; ++j) {
      float pm = fmaxf(fmaxf(sacc[0][j], sacc[1][j]), fmaxf(sacc[2][j], sacc[3][j]));
      pm = fmaxf(pm, __shfl_xor(pm, 1, 64));
      pm = fmaxf(pm, __shfl_xor(pm, 2, 64));
      pm = fmaxf(pm, __shfl_xor(pm, 4, 64));
      pm = fmaxf(pm, __shfl_xor(pm, 8, 64));
      float nm = fmaxf(m_[j], pm);
      corr[j] = __expf(m_[j] - nm);
      m_[j] = nm;
    }
#pragma unroll
    for (int st = 0; st < 4; ++st)
#pragma unroll
      for (int j = 0; j < 4; ++j)
        sacc[st][j] = __expf(sacc[st][j] - m_[j]);
#pragma unroll
    for (int j = 0; j < 4; ++j) {
      float rs = sacc[0][j] + sacc[1][j] + sacc[2][j] + sacc[3][j];
      rs += __shfl_xor(rs, 1, 64);
      rs += __shfl_xor(rs, 2, 64);
      rs += __shfl_xor(rs, 4, 64);
      rs += __shfl_xor(rs, 8, 64);
      l_[j] = l_[j] * corr[j] + rs;
#pragma unroll
      for (int ct = 0; ct < 4; ++ct) oacc[ct][j] *= corr[j];
    }
#pragma unroll
    for (int st = 0; st < 4; ++st)
#pragma unroll
      for (int j = 0; j < 4; ++j)
        P[w][qg * 4 + j][st * 16 + col] = f2bf(sacc[st][j]);
    __syncthreads();
    u16x8 pf[2];
#pragma unroll
    for (int half = 0; half < 2; ++half)
      pf[half] = *(const u16x8*)&P[w][col][half * 32 + qg * 8];
#pragma unroll
    for (int ct = 0; ct < 4; ++ct) {
#pragma unroll
      for (int half = 0; half < 2; ++half) {
        int sb = s0 + half * 32 + qg * 8;
        int ktv = kbase + (fk + sb) % kmod;
        u16x8 vfr = *(const u16x8*)&Vt[(size_t)(ch0 + ct * 16 + col) * 20480 + ktv];
        oacc[ct] = mfma16x16(pf[half], vfr, oacc[ct]);
      }
    }
    __syncthreads();
  }
#pragma unroll
  for (int ct = 0; ct < 4; ++ct)
#pragma unroll
    for (int j = 0; j < 4; ++j) {
      float val = oacc[ct][j] / l_[j];
      AO[(size_t)(qt0 + qg * 4 + j) * 512 + ch0 + ct * 16 + col] = f2bf(val);
    }
}

// ---------- launch ----------
extern "C" void kernel_launch(void* const* d_in, const int* in_sizes, int n_in,
                              void* d_out, int out_size, void* d_ws,
                              size_t ws_size, hipStream_t stream) {
  const float* video = (const float*)d_in[0];
  const float* audio = (const float*)d_in[1];
  const float* v_g = (const float*)d_in[2];
  const float* v_b = (const float*)d_in[3];
  const float* a_g = (const float*)d_in[4];
  const float* a_b = (const float*)d_in[5];
  const float* vqkv_w = (const float*)d_in[6];
  const float* vqkv_b = (const float*)d_in[7];
  const float* aqkv_w = (const float*)d_in[8];
  const float* aqkv_b = (const float*)d_in[9];
  const float* vp_w = (const float*)d_in[10];
  const float* vp_b = (const float*)d_in[11];
  const float* ap_w = (const float*)d_in[12];
  const float* ap_b = (const float*)d_in[13];

  char* ws = (char*)d_ws;
  float* stats = (float*)ws;                   // 512 B
  u16* Wv = (u16*)(ws + 1024);                 // 1536*512
  u16* Wa = Wv + 1536 * 512;                   // 1536*512
  u16* Pv = Wa + 1536 * 512;                   // 512*512
  u16* Pa = Pv + 512 * 512;                    // 512*512
  u16* XT = Pa + 512 * 512;                    // 20480*512 (reused as AO)
  u16* Vt = XT + 20480 * 512;                  // 512*20480
  // Q and K live in d_out (overwritten only by the final proj epilogues)
  u16* Qb = (u16*)d_out;                       // 20480*512
  u16* Kb = Qb + 20480 * 512;                  // 20480*512
  float* out_v = (float*)d_out;
  float* out_a = out_v + 8388608;

  stats_kernel<<<64, 256, 0, stream>>>(video, audio, stats);
  norm_video<<<2048, 256, 0, stream>>>(video, v_g, v_b, stats, XT);
  norm_audio<<<512, 256, 0, stream>>>(audio, a_g, a_b, stats, XT);
  cvt_all<<<2048, 256, 0, stream>>>(vqkv_w, aqkv_w, vp_w, ap_w, Wv);

  dim3 gv(128, 12);
  gemm_bt<0><<<gv, 256, 0, stream>>>(Wv, XT, vqkv_b, Qb, Kb, Vt, nullptr, nullptr, 0);
  dim3 ga(32, 12);
  gemm_bt<0><<<ga, 256, 0, stream>>>(Wa, XT + (size_t)16384 * 512, aqkv_b, Qb, Kb, Vt, nullptr, nullptr, 16384);

  // video attn: Tq=1024, W=512, keys = audio window; audio attn: Tq=256, W=2048, keys = video window
  flash_attn<<<8 * 16 * 16, 256, 0, stream>>>(Qb, Kb, Vt, XT, 1024, 512, 0, 16384, 256, 4096, 16);
  flash_attn<<<8 * 16 * 4, 256, 0, stream>>>(Qb, Kb, Vt, XT, 256, 2048, 16384, 0, 1024, 16384, 4);

  dim3 gp(128, 4);
  gemm_bt<2><<<gp, 256, 0, stream>>>(Pv, XT, vp_b, nullptr, nullptr, nullptr, out_v, video, 0);
  dim3 gq(32, 4);
  gemm_bt<3><<<gq, 256, 0, stream>>>(Pa, XT + (size_t)16384 * 512, ap_b, nullptr, nullptr, nullptr, out_a, audio, 0);
}

// Round 7
// 532.852 us; speedup vs baseline: 1.6593x; 1.6593x over previous
//
#include <hip/hip_runtime.h>
#include <hip/hip_bf16.h>

typedef unsigned short u16;
typedef u16 u16x8 __attribute__((ext_vector_type(8)));
typedef u16 u16x4 __attribute__((ext_vector_type(4)));
typedef float f32x4 __attribute__((ext_vector_type(4)));
typedef __bf16 bf16x8 __attribute__((ext_vector_type(8)));

// ---------- helpers ----------
static __device__ __forceinline__ u16 f2bf(float f) {
  __hip_bfloat16 h = __float2bfloat16(f);
  return __builtin_bit_cast(u16, h);
}

static __device__ __forceinline__ f32x4 mfma16x16(u16x8 a, u16x8 b, f32x4 c) {
  return __builtin_amdgcn_mfma_f32_16x16x32_bf16(
      __builtin_bit_cast(bf16x8, a), __builtin_bit_cast(bf16x8, b), c, 0, 0, 0);
}

// ---------- group-norm statistics, stage 1: partial sums ----------
// blocks 0..511: video  (g = b>>4 owns ch [16g,16g+16), f = b&15) — one
//   contiguous 16384-float slab: video[f, 16g.., :] per block.
// blocks 512..639: audio (g = (b-512)>>2, chunk = (b-512)&3) — contiguous
//   16384-float quarter of the group's 65536 floats.
__global__ void __launch_bounds__(256) stats_partial(
    const float* __restrict__ video, const float* __restrict__ audio,
    float* __restrict__ partials) {
  int b = blockIdx.x;
  int tid = threadIdx.x;
  const float* src;
  if (b < 512) {
    int g = b >> 4, f = b & 15;
    src = video + (size_t)f * 524288 + (size_t)(g * 16) * 1024;
  } else {
    int bb = b - 512;
    int g = bb >> 2, ck = bb & 3;
    src = audio + (size_t)(g * 16) * 4096 + ck * 16384;
  }
  float s1 = 0.f, s2 = 0.f;
#pragma unroll
  for (int it = 0; it < 16; ++it) {
    float4 v = *(const float4*)&src[it * 1024 + tid * 4];
    s1 += v.x + v.y + v.z + v.w;
    s2 += v.x * v.x + v.y * v.y + v.z * v.z + v.w * v.w;
  }
  __shared__ float r1[256], r2[256];
  r1[tid] = s1; r2[tid] = s2;
  __syncthreads();
  for (int s = 128; s > 0; s >>= 1) {
    if (tid < s) { r1[tid] += r1[tid + s]; r2[tid] += r2[tid + s]; }
    __syncthreads();
  }
  if (tid == 0) { partials[2 * b] = r1[0]; partials[2 * b + 1] = r2[0]; }
}

// ---------- stage 2: finalize mu / rsqrt(var+eps) per group ----------
__global__ void __launch_bounds__(64) stats_finalize(
    const float* __restrict__ partials, float* __restrict__ stats) {
  int g = threadIdx.x;  // 0..63
  int base, cnt;
  if (g < 32) { base = g * 16; cnt = 16; }
  else        { base = 512 + (g - 32) * 4; cnt = 4; }
  float s1 = 0.f, s2 = 0.f;
  for (int i = 0; i < cnt; ++i) {
    s1 += partials[2 * (base + i)];
    s2 += partials[2 * (base + i) + 1];
  }
  float n = (g < 32) ? 262144.f : 65536.f;
  float mu = s1 / n;
  float var = s2 / n - mu * mu;
  stats[2 * g] = mu;
  stats[2 * g + 1] = rsqrtf(var + 1e-5f);
}

// ---------- normalize + transpose to XT[t][c] (bf16) ----------
__global__ void __launch_bounds__(256) norm_video(
    const float* __restrict__ video, const float* __restrict__ gamma,
    const float* __restrict__ beta, const float* __restrict__ stats,
    u16* __restrict__ XT) {
  __shared__ float tile[64][65];
  int bid = blockIdx.x;
  int t0 = (bid % 256) * 64;  // token tile (within video, 16384 tokens)
  int c0 = (bid / 256) * 64;  // channel tile
  int f = t0 >> 10;
  int hw0 = t0 & 1023;
  int tx = threadIdx.x & 63, ty = threadIdx.x >> 6;
#pragma unroll
  for (int p = 0; p < 16; ++p) {
    int cl = p * 4 + ty;
    int c = c0 + cl;
    float x = video[(size_t)f * 524288 + (size_t)c * 1024 + hw0 + tx];
    int g = c >> 4;
    float xn = (x - stats[2 * g]) * stats[2 * g + 1] * gamma[c] + beta[c];
    tile[tx][cl] = xn;
  }
  __syncthreads();
#pragma unroll
  for (int p = 0; p < 16; ++p) {
    int tl = p * 4 + ty;
    XT[(size_t)(t0 + tl) * 512 + c0 + tx] = f2bf(tile[tl][tx]);
  }
}

__global__ void __launch_bounds__(256) norm_audio(
    const float* __restrict__ audio, const float* __restrict__ gamma,
    const float* __restrict__ beta, const float* __restrict__ stats,
    u16* __restrict__ XT) {
  __shared__ float tile[64][65];
  int bid = blockIdx.x;
  int t0 = (bid % 64) * 64;
  int c0 = (bid / 64) * 64;
  int tx = threadIdx.x & 63, ty = threadIdx.x >> 6;
#pragma unroll
  for (int p = 0; p < 16; ++p) {
    int cl = p * 4 + ty;
    int c = c0 + cl;
    float x = audio[(size_t)c * 4096 + t0 + tx];
    int g = 32 + (c >> 4);
    float xn = (x - stats[2 * g]) * stats[2 * g + 1] * gamma[c] + beta[c];
    tile[tx][cl] = xn;
  }
  __syncthreads();
#pragma unroll
  for (int p = 0; p < 16; ++p) {
    int tl = p * 4 + ty;
    XT[(size_t)(16384 + t0 + tl) * 512 + c0 + tx] = f2bf(tile[tl][tx]);
  }
}

// ---------- fused fp32 -> bf16 weight convert (Wv|Wa|Pv|Pa contiguous dst) ----------
__global__ void __launch_bounds__(256) cvt_all(
    const float* __restrict__ s0, const float* __restrict__ s1,
    const float* __restrict__ s2, const float* __restrict__ s3,
    u16* __restrict__ dst) {
  int i = (blockIdx.x * 256 + threadIdx.x) * 4;  // [0, 2097152)
  const float* src;
  int off;
  if (i < 786432)       { src = s0; off = 0; }
  else if (i < 1572864) { src = s1; off = 786432; }
  else if (i < 1835008) { src = s2; off = 1572864; }
  else                  { src = s3; off = 1835008; }
  float4 v = *(const float4*)&src[i - off];
  u16x4 pk;
  pk[0] = f2bf(v.x); pk[1] = f2bf(v.y); pk[2] = f2bf(v.z); pk[3] = f2bf(v.w);
  *(u16x4*)&dst[i] = pk;
}

// ---------- GEMM  C[m][n] = sum_k A[m][k] * B[n][k]   (K = 512) ----------
// MODE 0: qkv epilogue  -> Q[t][c] (x0.125), K[t][c], Vt[c][t], +bias
// MODE 2: video proj    -> d_out video += residual, +bias
// MODE 3: audio proj    -> d_out audio += residual, +bias
template <int MODE>
__global__ void __launch_bounds__(256, 2) gemm_bt(
    const u16* __restrict__ A, const u16* __restrict__ B,
    const float* __restrict__ bias, u16* __restrict__ Qo,
    u16* __restrict__ Ko, u16* __restrict__ Vt, float* __restrict__ FO,
    const float* __restrict__ RES, int t_off) {
  __shared__ u16 As[128][72];
  __shared__ u16 Bs[128][72];
  const int tid = threadIdx.x;
  const int lane = tid & 63;
  const int w = tid >> 6;
  const int wr = w >> 1, wc = w & 1;
  const int col = lane & 15, qg = lane >> 4;
  const int m0 = blockIdx.y * 128;
  const int n0 = blockIdx.x * 128;
  f32x4 acc[4][4] = {};
  for (int k0 = 0; k0 < 512; k0 += 64) {
#pragma unroll
    for (int p = 0; p < 4; ++p) {
      int chunk = p * 256 + tid;
      int row = chunk >> 3;
      int kk = (chunk & 7) * 8;
      *(u16x8*)&As[row][kk] = *(const u16x8*)&A[(size_t)(m0 + row) * 512 + k0 + kk];
      *(u16x8*)&Bs[row][kk] = *(const u16x8*)&B[(size_t)(n0 + row) * 512 + k0 + kk];
    }
    __syncthreads();
#pragma unroll
    for (int ks = 0; ks < 2; ++ks) {
      u16x8 af[4], bf[4];
#pragma unroll
      for (int mt = 0; mt < 4; ++mt)
        af[mt] = *(const u16x8*)&As[wr * 64 + mt * 16 + col][ks * 32 + qg * 8];
#pragma unroll
      for (int nt = 0; nt < 4; ++nt)
        bf[nt] = *(const u16x8*)&Bs[wc * 64 + nt * 16 + col][ks * 32 + qg * 8];
#pragma unroll
      for (int mt = 0; mt < 4; ++mt)
#pragma unroll
        for (int nt = 0; nt < 4; ++nt)
          acc[mt][nt] = mfma16x16(af[mt], bf[nt], acc[mt][nt]);
    }
    __syncthreads();
  }
  // epilogue
#pragma unroll
  for (int mt = 0; mt < 4; ++mt) {
    int o = m0 + wr * 64 + mt * 16 + qg * 4;
#pragma unroll
    for (int nt = 0; nt < 4; ++nt) {
      int t = n0 + wc * 64 + nt * 16 + col;
      float v0 = acc[mt][nt][0] + bias[o + 0];
      float v1 = acc[mt][nt][1] + bias[o + 1];
      float v2 = acc[mt][nt][2] + bias[o + 2];
      float v3 = acc[mt][nt][3] + bias[o + 3];
      if constexpr (MODE == 0) {
        int tg = t_off + t;
        if (o < 512) {
          // fold logit scale (1/8, exact in bf16) into Q
          u16x4 pk;
          pk[0] = f2bf(v0 * 0.125f); pk[1] = f2bf(v1 * 0.125f);
          pk[2] = f2bf(v2 * 0.125f); pk[3] = f2bf(v3 * 0.125f);
          *(u16x4*)&Qo[(size_t)tg * 512 + o] = pk;
        } else if (o < 1024) {
          u16x4 pk;
          pk[0] = f2bf(v0); pk[1] = f2bf(v1); pk[2] = f2bf(v2); pk[3] = f2bf(v3);
          *(u16x4*)&Ko[(size_t)tg * 512 + (o - 512)] = pk;
        } else {
          int vo = o - 1024;
          Vt[(size_t)(vo + 0) * 20480 + tg] = f2bf(v0);
          Vt[(size_t)(vo + 1) * 20480 + tg] = f2bf(v1);
          Vt[(size_t)(vo + 2) * 20480 + tg] = f2bf(v2);
          Vt[(size_t)(vo + 3) * 20480 + tg] = f2bf(v3);
        }
      } else if constexpr (MODE == 2) {
        int f = t >> 10, hw = t & 1023;
        size_t i0 = ((size_t)(f * 512 + o)) * 1024 + hw;
        FO[i0]        = RES[i0]        + v0;
        FO[i0 + 1024] = RES[i0 + 1024] + v1;
        FO[i0 + 2048] = RES[i0 + 2048] + v2;
        FO[i0 + 3072] = RES[i0 + 3072] + v3;
      } else {
        size_t i0 = (size_t)o * 4096 + t;
        FO[i0]         = RES[i0]         + v0;
        FO[i0 + 4096]  = RES[i0 + 4096]  + v1;
        FO[i0 + 8192]  = RES[i0 + 8192]  + v2;
        FO[i0 + 12288] = RES[i0 + 12288] + v3;
      }
    }
  }
}

// ---------- flash attention (windowed, wrap-around gather, no mask) ----------
// Q pre-scaled by 0.125. Block = 4 waves, wave owns 16 q-rows.
// key token index: kt = kbase + (f*kstep + s) % kmod
__global__ void __launch_bounds__(256, 2) flash_attn(
    const u16* __restrict__ Q, const u16* __restrict__ K,
    const u16* __restrict__ Vt, u16* __restrict__ AO, int Tq, int W,
    int qt_base, int kbase, int kstep, int kmod, int nttiles) {
  __shared__ u16 P[4][16][72];
  int bid = blockIdx.x;
  int tt = bid % nttiles;
  int f = (bid / nttiles) & 15;
  int h = bid / (nttiles * 16);
  int tid = threadIdx.x;
  int lane = tid & 63;
  int w = tid >> 6;
  int col = lane & 15, qg = lane >> 4;
  int ch0 = h * 64;
  int qt0 = qt_base + f * Tq + tt * 64 + w * 16;
  u16x8 qf[2];
#pragma unroll
  for (int kk = 0; kk < 2; ++kk)
    qf[kk] = *(const u16x8*)&Q[(size_t)(qt0 + col) * 512 + ch0 + kk * 32 + qg * 8];
  f32x4 oacc[4] = {};
  float m_[4], l_[4];
#pragma unroll
  for (int j = 0; j < 4; ++j) { m_[j] = -1e30f; l_[j] = 0.f; }
  int fk = f * kstep;
  for (int s0 = 0; s0 < W; s0 += 64) {
    f32x4 sacc[4] = {};
#pragma unroll
    for (int st = 0; st < 4; ++st) {
      int s = s0 + st * 16 + col;
      int kt = kbase + (fk + s) % kmod;
      const u16* kr = &K[(size_t)kt * 512 + ch0];
#pragma unroll
      for (int kk = 0; kk < 2; ++kk) {
        u16x8 bfr = *(const u16x8*)&kr[kk * 32 + qg * 8];
        sacc[st] = mfma16x16(qf[kk], bfr, sacc[st]);
      }
    }
    float corr[4];
#pragma unroll
    for (int j = 0; j < 4; ++j) {
      float pm = fmaxf(fmaxf(sacc[0][j], sacc[1][j]), fmaxf(sacc[2][j], sacc[3][j]));
      pm = fmaxf(pm, __shfl_xor(pm, 1, 64));
      pm = fmaxf(pm, __shfl_xor(pm, 2, 64));
      pm = fmaxf(pm, __shfl_xor(pm, 4, 64));
      pm = fmaxf(pm, __shfl_xor(pm, 8, 64));
      float nm = fmaxf(m_[j], pm);
      corr[j] = __expf(m_[j] - nm);
      m_[j] = nm;
    }
#pragma unroll
    for (int st = 0; st < 4; ++st)
#pragma unroll
      for (int j = 0; j < 4; ++j)
        sacc[st][j] = __expf(sacc[st][j] - m_[j]);
#pragma unroll
    for (int j = 0; j < 4; ++j) {
      float rs = sacc[0][j] + sacc[1][j] + sacc[2][j] + sacc[3][j];
      rs += __shfl_xor(rs, 1, 64);
      rs += __shfl_xor(rs, 2, 64);
      rs += __shfl_xor(rs, 4, 64);
      rs += __shfl_xor(rs, 8, 64);
      l_[j] = l_[j] * corr[j] + rs;
#pragma unroll
      for (int ct = 0; ct < 4; ++ct) oacc[ct][j] *= corr[j];
    }
#pragma unroll
    for (int st = 0; st < 4; ++st)
#pragma unroll
      for (int j = 0; j < 4; ++j)
        P[w][qg * 4 + j][st * 16 + col] = f2bf(sacc[st][j]);
    __syncthreads();
    u16x8 pf[2];
#pragma unroll
    for (int half = 0; half < 2; ++half)
      pf[half] = *(const u16x8*)&P[w][col][half * 32 + qg * 8];
#pragma unroll
    for (int ct = 0; ct < 4; ++ct) {
#pragma unroll
      for (int half = 0; half < 2; ++half) {
        int sb = s0 + half * 32 + qg * 8;
        int ktv = kbase + (fk + sb) % kmod;
        u16x8 vfr = *(const u16x8*)&Vt[(size_t)(ch0 + ct * 16 + col) * 20480 + ktv];
        oacc[ct] = mfma16x16(pf[half], vfr, oacc[ct]);
      }
    }
    __syncthreads();
  }
#pragma unroll
  for (int ct = 0; ct < 4; ++ct)
#pragma unroll
    for (int j = 0; j < 4; ++j) {
      float val = oacc[ct][j] / l_[j];
      AO[(size_t)(qt0 + qg * 4 + j) * 512 + ch0 + ct * 16 + col] = f2bf(val);
    }
}

// ---------- launch ----------
extern "C" void kernel_launch(void* const* d_in, const int* in_sizes, int n_in,
                              void* d_out, int out_size, void* d_ws,
                              size_t ws_size, hipStream_t stream) {
  const float* video = (const float*)d_in[0];
  const float* audio = (const float*)d_in[1];
  const float* v_g = (const float*)d_in[2];
  const float* v_b = (const float*)d_in[3];
  const float* a_g = (const float*)d_in[4];
  const float* a_b = (const float*)d_in[5];
  const float* vqkv_w = (const float*)d_in[6];
  const float* vqkv_b = (const float*)d_in[7];
  const float* aqkv_w = (const float*)d_in[8];
  const float* aqkv_b = (const float*)d_in[9];
  const float* vp_w = (const float*)d_in[10];
  const float* vp_b = (const float*)d_in[11];
  const float* ap_w = (const float*)d_in[12];
  const float* ap_b = (const float*)d_in[13];

  char* ws = (char*)d_ws;
  float* stats = (float*)ws;                   // 512 B
  float* partials = (float*)(ws + 512);        // 640*2 floats = 5120 B
  u16* Wv = (u16*)(ws + 8192);                 // 1536*512
  u16* Wa = Wv + 1536 * 512;                   // 1536*512
  u16* Pv = Wa + 1536 * 512;                   // 512*512
  u16* Pa = Pv + 512 * 512;                    // 512*512
  u16* XT = Pa + 512 * 512;                    // 20480*512 (reused as AO)
  u16* Vt = XT + 20480 * 512;                  // 512*20480
  // Q and K live in d_out (overwritten only by the final proj epilogues)
  u16* Qb = (u16*)d_out;                       // 20480*512
  u16* Kb = Qb + 20480 * 512;                  // 20480*512
  float* out_v = (float*)d_out;
  float* out_a = out_v + 8388608;

  stats_partial<<<640, 256, 0, stream>>>(video, audio, partials);
  stats_finalize<<<1, 64, 0, stream>>>(partials, stats);
  norm_video<<<2048, 256, 0, stream>>>(video, v_g, v_b, stats, XT);
  norm_audio<<<512, 256, 0, stream>>>(audio, a_g, a_b, stats, XT);
  cvt_all<<<2048, 256, 0, stream>>>(vqkv_w, aqkv_w, vp_w, ap_w, Wv);

  dim3 gv(128, 12);
  gemm_bt<0><<<gv, 256, 0, stream>>>(Wv, XT, vqkv_b, Qb, Kb, Vt, nullptr, nullptr, 0);
  dim3 ga(32, 12);
  gemm_bt<0><<<ga, 256, 0, stream>>>(Wa, XT + (size_t)16384 * 512, aqkv_b, Qb, Kb, Vt, nullptr, nullptr, 16384);

  // video attn: Tq=1024, W=512, keys = audio window; audio attn: Tq=256, W=2048, keys = video window
  flash_attn<<<8 * 16 * 16, 256, 0, stream>>>(Qb, Kb, Vt, XT, 1024, 512, 0, 16384, 256, 4096, 16);
  flash_attn<<<8 * 16 * 4, 256, 0, stream>>>(Qb, Kb, Vt, XT, 256, 2048, 16384, 0, 1024, 16384, 4);

  dim3 gp(128, 4);
  gemm_bt<2><<<gp, 256, 0, stream>>>(Pv, XT, vp_b, nullptr, nullptr, nullptr, out_v, video, 0);
  dim3 gq(32, 4);
  gemm_bt<3><<<gq, 256, 0, stream>>>(Pa, XT + (size_t)16384 * 512, ap_b, nullptr, nullptr, nullptr, out_a, audio, 0);
}

// Round 8
// 502.894 us; speedup vs baseline: 1.7582x; 1.0596x over previous
//
#include <hip/hip_runtime.h>
#include <hip/hip_bf16.h>

typedef unsigned short u16;
typedef u16 u16x8 __attribute__((ext_vector_type(8)));
typedef u16 u16x4 __attribute__((ext_vector_type(4)));
typedef float f32x4 __attribute__((ext_vector_type(4)));
typedef __bf16 bf16x8 __attribute__((ext_vector_type(8)));

// ---------- helpers ----------
static __device__ __forceinline__ u16 f2bf(float f) {
  __hip_bfloat16 h = __float2bfloat16(f);
  return __builtin_bit_cast(u16, h);
}

static __device__ __forceinline__ f32x4 mfma16x16(u16x8 a, u16x8 b, f32x4 c) {
  return __builtin_amdgcn_mfma_f32_16x16x32_bf16(
      __builtin_bit_cast(bf16x8, a), __builtin_bit_cast(bf16x8, b), c, 0, 0, 0);
}

// ---------- group-norm statistics, stage 1: partial sums ----------
__global__ void __launch_bounds__(256) stats_partial(
    const float* __restrict__ video, const float* __restrict__ audio,
    float* __restrict__ partials) {
  int b = blockIdx.x;
  int tid = threadIdx.x;
  const float* src;
  if (b < 512) {
    int g = b >> 4, f = b & 15;
    src = video + (size_t)f * 524288 + (size_t)(g * 16) * 1024;
  } else {
    int bb = b - 512;
    int g = bb >> 2, ck = bb & 3;
    src = audio + (size_t)(g * 16) * 4096 + ck * 16384;
  }
  float s1 = 0.f, s2 = 0.f;
#pragma unroll
  for (int it = 0; it < 16; ++it) {
    float4 v = *(const float4*)&src[it * 1024 + tid * 4];
    s1 += v.x + v.y + v.z + v.w;
    s2 += v.x * v.x + v.y * v.y + v.z * v.z + v.w * v.w;
  }
  __shared__ float r1[256], r2[256];
  r1[tid] = s1; r2[tid] = s2;
  __syncthreads();
  for (int s = 128; s > 0; s >>= 1) {
    if (tid < s) { r1[tid] += r1[tid + s]; r2[tid] += r2[tid + s]; }
    __syncthreads();
  }
  if (tid == 0) { partials[2 * b] = r1[0]; partials[2 * b + 1] = r2[0]; }
}

// ---------- stage 2: finalize mu / rsqrt(var+eps) per group ----------
__global__ void __launch_bounds__(64) stats_finalize(
    const float* __restrict__ partials, float* __restrict__ stats) {
  int g = threadIdx.x;  // 0..63
  int base, cnt;
  if (g < 32) { base = g * 16; cnt = 16; }
  else        { base = 512 + (g - 32) * 4; cnt = 4; }
  float s1 = 0.f, s2 = 0.f;
  for (int i = 0; i < cnt; ++i) {
    s1 += partials[2 * (base + i)];
    s2 += partials[2 * (base + i) + 1];
  }
  float n = (g < 32) ? 262144.f : 65536.f;
  float mu = s1 / n;
  float var = s2 / n - mu * mu;
  stats[2 * g] = mu;
  stats[2 * g + 1] = rsqrtf(var + 1e-5f);
}

// ---------- normalize + transpose to XT[t][c] (bf16) ----------
__global__ void __launch_bounds__(256) norm_video(
    const float* __restrict__ video, const float* __restrict__ gamma,
    const float* __restrict__ beta, const float* __restrict__ stats,
    u16* __restrict__ XT) {
  __shared__ float tile[64][65];
  int bid = blockIdx.x;
  int t0 = (bid % 256) * 64;  // token tile (within video, 16384 tokens)
  int c0 = (bid / 256) * 64;  // channel tile
  int f = t0 >> 10;
  int hw0 = t0 & 1023;
  int tx = threadIdx.x & 63, ty = threadIdx.x >> 6;
#pragma unroll
  for (int p = 0; p < 16; ++p) {
    int cl = p * 4 + ty;
    int c = c0 + cl;
    float x = video[(size_t)f * 524288 + (size_t)c * 1024 + hw0 + tx];
    int g = c >> 4;
    float xn = (x - stats[2 * g]) * stats[2 * g + 1] * gamma[c] + beta[c];
    tile[tx][cl] = xn;
  }
  __syncthreads();
#pragma unroll
  for (int p = 0; p < 16; ++p) {
    int tl = p * 4 + ty;
    XT[(size_t)(t0 + tl) * 512 + c0 + tx] = f2bf(tile[tl][tx]);
  }
}

__global__ void __launch_bounds__(256) norm_audio(
    const float* __restrict__ audio, const float* __restrict__ gamma,
    const float* __restrict__ beta, const float* __restrict__ stats,
    u16* __restrict__ XT) {
  __shared__ float tile[64][65];
  int bid = blockIdx.x;
  int t0 = (bid % 64) * 64;
  int c0 = (bid / 64) * 64;
  int tx = threadIdx.x & 63, ty = threadIdx.x >> 6;
#pragma unroll
  for (int p = 0; p < 16; ++p) {
    int cl = p * 4 + ty;
    int c = c0 + cl;
    float x = audio[(size_t)c * 4096 + t0 + tx];
    int g = 32 + (c >> 4);
    float xn = (x - stats[2 * g]) * stats[2 * g + 1] * gamma[c] + beta[c];
    tile[tx][cl] = xn;
  }
  __syncthreads();
#pragma unroll
  for (int p = 0; p < 16; ++p) {
    int tl = p * 4 + ty;
    XT[(size_t)(16384 + t0 + tl) * 512 + c0 + tx] = f2bf(tile[tl][tx]);
  }
}

// ---------- fused fp32 -> bf16 weight convert (Wv|Wa|Pv|Pa contiguous dst) ----------
__global__ void __launch_bounds__(256) cvt_all(
    const float* __restrict__ s0, const float* __restrict__ s1,
    const float* __restrict__ s2, const float* __restrict__ s3,
    u16* __restrict__ dst) {
  int i = (blockIdx.x * 256 + threadIdx.x) * 4;  // [0, 2097152)
  const float* src;
  int off;
  if (i < 786432)       { src = s0; off = 0; }
  else if (i < 1572864) { src = s1; off = 786432; }
  else if (i < 1835008) { src = s2; off = 1572864; }
  else                  { src = s3; off = 1835008; }
  float4 v = *(const float4*)&src[i - off];
  u16x4 pk;
  pk[0] = f2bf(v.x); pk[1] = f2bf(v.y); pk[2] = f2bf(v.z); pk[3] = f2bf(v.w);
  *(u16x4*)&dst[i] = pk;
}

// ---------- GEMM  C[m][n] = sum_k A[m][k] * B[n][k]   (K = 512) ----------
// MODE 0: qkv epilogue  -> Q[t][c] (x0.125), K[t][c], Vt[c][t], +bias
// MODE 2: video proj    -> d_out video += residual, +bias
// MODE 3: audio proj    -> d_out audio += residual, +bias
template <int MODE>
__global__ void __launch_bounds__(256, 2) gemm_bt(
    const u16* __restrict__ A, const u16* __restrict__ B,
    const float* __restrict__ bias, u16* __restrict__ Qo,
    u16* __restrict__ Ko, u16* __restrict__ Vt, float* __restrict__ FO,
    const float* __restrict__ RES, int t_off) {
  __shared__ u16 As[128][72];
  __shared__ u16 Bs[128][72];
  const int tid = threadIdx.x;
  const int lane = tid & 63;
  const int w = tid >> 6;
  const int wr = w >> 1, wc = w & 1;
  const int col = lane & 15, qg = lane >> 4;
  const int m0 = blockIdx.y * 128;
  const int n0 = blockIdx.x * 128;
  f32x4 acc[4][4] = {};
  for (int k0 = 0; k0 < 512; k0 += 64) {
#pragma unroll
    for (int p = 0; p < 4; ++p) {
      int chunk = p * 256 + tid;
      int row = chunk >> 3;
      int kk = (chunk & 7) * 8;
      *(u16x8*)&As[row][kk] = *(const u16x8*)&A[(size_t)(m0 + row) * 512 + k0 + kk];
      *(u16x8*)&Bs[row][kk] = *(const u16x8*)&B[(size_t)(n0 + row) * 512 + k0 + kk];
    }
    __syncthreads();
#pragma unroll
    for (int ks = 0; ks < 2; ++ks) {
      u16x8 af[4], bf[4];
#pragma unroll
      for (int mt = 0; mt < 4; ++mt)
        af[mt] = *(const u16x8*)&As[wr * 64 + mt * 16 + col][ks * 32 + qg * 8];
#pragma unroll
      for (int nt = 0; nt < 4; ++nt)
        bf[nt] = *(const u16x8*)&Bs[wc * 64 + nt * 16 + col][ks * 32 + qg * 8];
#pragma unroll
      for (int mt = 0; mt < 4; ++mt)
#pragma unroll
        for (int nt = 0; nt < 4; ++nt)
          acc[mt][nt] = mfma16x16(af[mt], bf[nt], acc[mt][nt]);
    }
    __syncthreads();
  }
  // epilogue
#pragma unroll
  for (int mt = 0; mt < 4; ++mt) {
    int o = m0 + wr * 64 + mt * 16 + qg * 4;
#pragma unroll
    for (int nt = 0; nt < 4; ++nt) {
      int t = n0 + wc * 64 + nt * 16 + col;
      float v0 = acc[mt][nt][0] + bias[o + 0];
      float v1 = acc[mt][nt][1] + bias[o + 1];
      float v2 = acc[mt][nt][2] + bias[o + 2];
      float v3 = acc[mt][nt][3] + bias[o + 3];
      if constexpr (MODE == 0) {
        int tg = t_off + t;
        if (o < 512) {
          // fold logit scale (1/8, exact in bf16) into Q
          u16x4 pk;
          pk[0] = f2bf(v0 * 0.125f); pk[1] = f2bf(v1 * 0.125f);
          pk[2] = f2bf(v2 * 0.125f); pk[3] = f2bf(v3 * 0.125f);
          *(u16x4*)&Qo[(size_t)tg * 512 + o] = pk;
        } else if (o < 1024) {
          u16x4 pk;
          pk[0] = f2bf(v0); pk[1] = f2bf(v1); pk[2] = f2bf(v2); pk[3] = f2bf(v3);
          *(u16x4*)&Ko[(size_t)tg * 512 + (o - 512)] = pk;
        } else {
          int vo = o - 1024;
          Vt[(size_t)(vo + 0) * 20480 + tg] = f2bf(v0);
          Vt[(size_t)(vo + 1) * 20480 + tg] = f2bf(v1);
          Vt[(size_t)(vo + 2) * 20480 + tg] = f2bf(v2);
          Vt[(size_t)(vo + 3) * 20480 + tg] = f2bf(v3);
        }
      } else if constexpr (MODE == 2) {
        int f = t >> 10, hw = t & 1023;
        size_t i0 = ((size_t)(f * 512 + o)) * 1024 + hw;
        FO[i0]        = RES[i0]        + v0;
        FO[i0 + 1024] = RES[i0 + 1024] + v1;
        FO[i0 + 2048] = RES[i0 + 2048] + v2;
        FO[i0 + 3072] = RES[i0 + 3072] + v3;
      } else {
        size_t i0 = (size_t)o * 4096 + t;
        FO[i0]         = RES[i0]         + v0;
        FO[i0 + 4096]  = RES[i0 + 4096]  + v1;
        FO[i0 + 8192]  = RES[i0 + 8192]  + v2;
        FO[i0 + 12288] = RES[i0 + 12288] + v3;
      }
    }
  }
}

// ---------- flash attention (windowed, wrap-around gather, no mask) ----------
// Q pre-scaled by 0.125. Block = 4 waves, wave owns 16 q-rows.
// key token index: kt = kbase + (f*kstep + s) % kmod
// XCD-chunked swizzle: blocks sharing one head land on one XCD's L2.
__global__ void __launch_bounds__(256, 2) flash_attn(
    const u16* __restrict__ Q, const u16* __restrict__ K,
    const u16* __restrict__ Vt, u16* __restrict__ AO, int Tq, int W,
    int qt_base, int kbase, int kstep, int kmod, int nttiles) {
  __shared__ u16 P[4][16][72];
  int nwg = gridDim.x;  // 2048 (video) or 512 (audio), both % 8 == 0
  int bid = (blockIdx.x & 7) * (nwg >> 3) + (blockIdx.x >> 3);
  int tt = bid % nttiles;
  int f = (bid / nttiles) & 15;
  int h = bid / (nttiles * 16);
  int tid = threadIdx.x;
  int lane = tid & 63;
  int w = tid >> 6;
  int col = lane & 15, qg = lane >> 4;
  int ch0 = h * 64;
  int qt0 = qt_base + f * Tq + tt * 64 + w * 16;
  u16x8 qf[2];
#pragma unroll
  for (int kk = 0; kk < 2; ++kk)
    qf[kk] = *(const u16x8*)&Q[(size_t)(qt0 + col) * 512 + ch0 + kk * 32 + qg * 8];
  f32x4 oacc[4] = {};
  float m_[4], l_[4];
#pragma unroll
  for (int j = 0; j < 4; ++j) { m_[j] = -1e30f; l_[j] = 0.f; }
  int fk = f * kstep;
  for (int s0 = 0; s0 < W; s0 += 64) {
    f32x4 sacc[4] = {};
#pragma unroll
    for (int st = 0; st < 4; ++st) {
      int s = s0 + st * 16 + col;
      int kt = kbase + (fk + s) % kmod;
      const u16* kr = &K[(size_t)kt * 512 + ch0];
#pragma unroll
      for (int kk = 0; kk < 2; ++kk) {
        u16x8 bfr = *(const u16x8*)&kr[kk * 32 + qg * 8];
        sacc[st] = mfma16x16(qf[kk], bfr, sacc[st]);
      }
    }
    float corr[4];
#pragma unroll
    for (int j = 0; j < 4; ++j) {
      float pm = fmaxf(fmaxf(sacc[0][j], sacc[1][j]), fmaxf(sacc[2][j], sacc[3][j]));
      pm = fmaxf(pm, __shfl_xor(pm, 1, 64));
      pm = fmaxf(pm, __shfl_xor(pm, 2, 64));
      pm = fmaxf(pm, __shfl_xor(pm, 4, 64));
      pm = fmaxf(pm, __shfl_xor(pm, 8, 64));
      float nm = fmaxf(m_[j], pm);
      corr[j] = __expf(m_[j] - nm);
      m_[j] = nm;
    }
#pragma unroll
    for (int st = 0; st < 4; ++st)
#pragma unroll
      for (int j = 0; j < 4; ++j)
        sacc[st][j] = __expf(sacc[st][j] - m_[j]);
#pragma unroll
    for (int j = 0; j < 4; ++j) {
      float rs = sacc[0][j] + sacc[1][j] + sacc[2][j] + sacc[3][j];
      rs += __shfl_xor(rs, 1, 64);
      rs += __shfl_xor(rs, 2, 64);
      rs += __shfl_xor(rs, 4, 64);
      rs += __shfl_xor(rs, 8, 64);
      l_[j] = l_[j] * corr[j] + rs;
#pragma unroll
      for (int ct = 0; ct < 4; ++ct) oacc[ct][j] *= corr[j];
    }
    // P is wave-private (indexed by own w) -> no __syncthreads needed;
    // wave-local LDS RAW ordering is enforced by compiler lgkmcnt waits.
#pragma unroll
    for (int st = 0; st < 4; ++st)
#pragma unroll
      for (int j = 0; j < 4; ++j)
        P[w][qg * 4 + j][st * 16 + col] = f2bf(sacc[st][j]);
    u16x8 pf[2];
#pragma unroll
    for (int half = 0; half < 2; ++half)
      pf[half] = *(const u16x8*)&P[w][col][half * 32 + qg * 8];
#pragma unroll
    for (int ct = 0; ct < 4; ++ct) {
#pragma unroll
      for (int half = 0; half < 2; ++half) {
        int sb = s0 + half * 32 + qg * 8;
        int ktv = kbase + (fk + sb) % kmod;
        u16x8 vfr = *(const u16x8*)&Vt[(size_t)(ch0 + ct * 16 + col) * 20480 + ktv];
        oacc[ct] = mfma16x16(pf[half], vfr, oacc[ct]);
      }
    }
  }
#pragma unroll
  for (int ct = 0; ct < 4; ++ct)
#pragma unroll
    for (int j = 0; j < 4; ++j) {
      float val = oacc[ct][j] / l_[j];
      AO[(size_t)(qt0 + qg * 4 + j) * 512 + ch0 + ct * 16 + col] = f2bf(val);
    }
}

// ---------- launch ----------
extern "C" void kernel_launch(void* const* d_in, const int* in_sizes, int n_in,
                              void* d_out, int out_size, void* d_ws,
                              size_t ws_size, hipStream_t stream) {
  const float* video = (const float*)d_in[0];
  const float* audio = (const float*)d_in[1];
  const float* v_g = (const float*)d_in[2];
  const float* v_b = (const float*)d_in[3];
  const float* a_g = (const float*)d_in[4];
  const float* a_b = (const float*)d_in[5];
  const float* vqkv_w = (const float*)d_in[6];
  const float* vqkv_b = (const float*)d_in[7];
  const float* aqkv_w = (const float*)d_in[8];
  const float* aqkv_b = (const float*)d_in[9];
  const float* vp_w = (const float*)d_in[10];
  const float* vp_b = (const float*)d_in[11];
  const float* ap_w = (const float*)d_in[12];
  const float* ap_b = (const float*)d_in[13];

  char* ws = (char*)d_ws;
  float* stats = (float*)ws;                   // 512 B
  float* partials = (float*)(ws + 512);        // 640*2 floats = 5120 B
  u16* Wv = (u16*)(ws + 8192);                 // 1536*512
  u16* Wa = Wv + 1536 * 512;                   // 1536*512
  u16* Pv = Wa + 1536 * 512;                   // 512*512
  u16* Pa = Pv + 512 * 512;                    // 512*512
  u16* XT = Pa + 512 * 512;                    // 20480*512 (reused as AO)
  u16* Vt = XT + 20480 * 512;                  // 512*20480
  // Q and K live in d_out (overwritten only by the final proj epilogues)
  u16* Qb = (u16*)d_out;                       // 20480*512
  u16* Kb = Qb + 20480 * 512;                  // 20480*512
  float* out_v = (float*)d_out;
  float* out_a = out_v + 8388608;

  stats_partial<<<640, 256, 0, stream>>>(video, audio, partials);
  stats_finalize<<<1, 64, 0, stream>>>(partials, stats);
  norm_video<<<2048, 256, 0, stream>>>(video, v_g, v_b, stats, XT);
  norm_audio<<<512, 256, 0, stream>>>(audio, a_g, a_b, stats, XT);
  cvt_all<<<2048, 256, 0, stream>>>(vqkv_w, aqkv_w, vp_w, ap_w, Wv);

  dim3 gv(128, 12);
  gemm_bt<0><<<gv, 256, 0, stream>>>(Wv, XT, vqkv_b, Qb, Kb, Vt, nullptr, nullptr, 0);
  dim3 ga(32, 12);
  gemm_bt<0><<<ga, 256, 0, stream>>>(Wa, XT + (size_t)16384 * 512, aqkv_b, Qb, Kb, Vt, nullptr, nullptr, 16384);

  // video attn: Tq=1024, W=512, keys = audio window; audio attn: Tq=256, W=2048, keys = video window
  flash_attn<<<8 * 16 * 16, 256, 0, stream>>>(Qb, Kb, Vt, XT, 1024, 512, 0, 16384, 256, 4096, 16);
  flash_attn<<<8 * 16 * 4, 256, 0, stream>>>(Qb, Kb, Vt, XT, 256, 2048, 16384, 0, 1024, 16384, 4);

  dim3 gp(128, 4);
  gemm_bt<2><<<gp, 256, 0, stream>>>(Pv, XT, vp_b, nullptr, nullptr, nullptr, out_v, video, 0);
  dim3 gq(32, 4);
  gemm_bt<3><<<gq, 256, 0, stream>>>(Pa, XT + (size_t)16384 * 512, ap_b, nullptr, nullptr, nullptr, out_a, audio, 0);
}